// Round 7
// baseline (367.615 us; speedup 1.0000x reference)
//
#include <hip/hip_runtime.h>
#include <hip/hip_bf16.h>
#include <cstdint>

typedef __bf16 bf16;
typedef __bf16 bf16x8 __attribute__((ext_vector_type(8)));
typedef float  f32x4  __attribute__((ext_vector_type(4)));

#define B_   2
#define T_   2048
#define D_   2048
#define H_   16
#define HD_  128

// async global->LDS, 16 B per lane (m97: the 874 TF enabler).
// LDS dest must be wave-uniform base + lane*16 -> lanes stay contiguous in
// physical-slot order; we permute the GLOBAL side per-lane for XOR swizzles.
typedef __attribute__((address_space(3))) void       lds_void;
typedef __attribute__((address_space(1))) const void gbl_void;
__device__ __forceinline__ void glds16(const bf16* g, bf16* l) {
    __builtin_amdgcn_global_load_lds((gbl_void*)g, (lds_void*)l, 16, 0, 0);
}

// ---------------------------------------------------------------------------
// fp32 -> bf16 pre-convert (grid-stride, float4 -> 4x bf16 pack)
// ---------------------------------------------------------------------------
__device__ __forceinline__ ushort4 cvt4(const float4 v) {
    union { bf16 h[4]; ushort4 u; } pk;
    pk.h[0] = (bf16)v.x; pk.h[1] = (bf16)v.y;
    pk.h[2] = (bf16)v.z; pk.h[3] = (bf16)v.w;
    return pk.u;
}

__global__ __launch_bounds__(256) void convert_xw_kernel(
    const float* __restrict__ x, const float* __restrict__ wqkv,
    bf16* __restrict__ xb, bf16* __restrict__ wqkvb)
{
    const int NX = (B_ * T_ * D_) / 4;          // 2,097,152 float4
    const int NT = NX + (3 * D_ * D_) / 4;      // + 3,145,728
    for (int g = blockIdx.x * blockDim.x + threadIdx.x; g < NT;
         g += gridDim.x * blockDim.x) {
        if (g < NX) ((ushort4*)xb)[g]      = cvt4(((const float4*)x)[g]);
        else        ((ushort4*)wqkvb)[g-NX] = cvt4(((const float4*)wqkv)[g-NX]);
    }
}

__global__ __launch_bounds__(256) void convert_wo_kernel(
    const float* __restrict__ wo, bf16* __restrict__ wob)
{
    const int N = (D_ * D_) / 4;                // 1,048,576 float4
    for (int g = blockIdx.x * blockDim.x + threadIdx.x; g < N;
         g += gridDim.x * blockDim.x)
        ((ushort4*)wob)[g] = cvt4(((const float4*)wo)[g]);
}

// ---------------------------------------------------------------------------
// m97-style NT-GEMM core with XOR-swizzled LDS: C[128x128], A[M][K], W[N][K]
// (still used by proj_gemm; qkv upgraded to the 8-phase 256^2 core below)
// ---------------------------------------------------------------------------
__device__ __forceinline__ void gemm_core_glds(
    const bf16* __restrict__ A, const bf16* __restrict__ W, int K,
    int bm, int bn, int tid, f32x4 (&acc)[4][4],
    bf16* lds_a, bf16* lds_b)
{
    const int lane = tid & 63, quad = lane >> 4, lcol = lane & 15;
    const int wave = tid >> 6;
    const int wm = (wave >> 1) * 64, wn2 = (wave & 1) * 32;
    const int sw = lcol & 7;                          // read-side swizzle key
    const int sr = tid >> 3, pc = tid & 7;            // staging row / physical chunk
    const int sc = (pc ^ (sr & 7)) * 8;               // logical col group fetched
    const bf16* abase = A + (size_t)(bm * 128 + sr) * K + sc;
    const bf16* bbase = W + (size_t)(bn * 128 + sr) * K + sc;
    bf16* la = lds_a + sr * 64 + pc * 8;              // = lds_a + tid*8 elems
    bf16* lb = lds_b + sr * 64 + pc * 8;

    for (int k0 = 0; k0 < K; k0 += 64) {
        __syncthreads();
#pragma unroll
        for (int p = 0; p < 4; p++) {                 // (sr+32p)&7 == sr&7
            glds16(abase + k0 + (size_t)32 * p * K, la + 2048 * p);
            glds16(bbase + k0 + (size_t)32 * p * K, lb + 2048 * p);
        }
        __syncthreads();
#pragma unroll
        for (int kk = 0; kk < 2; kk++) {
            bf16x8 af[4], bfr[4];
#pragma unroll
            for (int i = 0; i < 4; i++)
                af[i] = *(const bf16x8*)&lds_a[(wm + i * 16 + lcol) * 64 +
                                               (((kk * 4 + quad) ^ sw) * 8)];
#pragma unroll
            for (int j = 0; j < 4; j++) {
                const int row = wn2 + (j & 1) * 16 + (j >> 1) * 64 + lcol;
                bfr[j] = *(const bf16x8*)&lds_b[row * 64 +
                                                (((kk * 4 + quad) ^ sw) * 8)];
            }
#pragma unroll
            for (int i = 0; i < 4; i++)
#pragma unroll
                for (int j = 0; j < 4; j++)
                    acc[i][j] = __builtin_amdgcn_mfma_f32_16x16x32_bf16(af[i], bfr[j], acc[i][j], 0, 0, 0);
        }
    }
}

// ---------------------------------------------------------------------------
// QKV projection, R12: 256x256-tile 8-phase deep-pipelined GEMM (T3+T4).
// Old 128^2 2-barrier core measured 852 TF = the m97 structural ceiling
// (MfmaUtil 37%); the proven escape is counted-vmcnt pipelining (m218:
// counted-vs-drain0 = +38..73%; m201: 1563 TF at 256^2).
//
// Geometry: BM=BN=256, BK=64, 512 thr = 8 waves (4M x 2N) -> per-wave
// C = 64x128 (acc[4][8]) so RoPE pairs (d, d+64) stay register-local.
// LDS = 8 half-tile slots x 16KB = 128KB: slot(h) = h%8 for half index
// h = 4t+kind, kind = {0:A rows0-127, 1:A rows128-255, 2:B nrows0-127,
// 3:B nrows128-255} of K-tile t. XOR swizzle identical to gemm_core
// (proven 0 bank conflicts).
//
// Pipeline (WAR-checked): at tile t, stage B(t+1) after the boundary
// barrier, stage A(t+2) after a mid-tile pacing barrier. Boundary wait =
// vmcnt(4): retains A(t+1)'s 4 loads in flight ACROSS the barrier (never
// drains to 0 except the final tile). Overwrite windows: B slots of tile
// t are rewritten at tile t+1's post-boundary (all reads of t done);
// A slots of tile t rewritten after tile t's pacing barrier (A reads are
// front-loaded before it). Reads: A(8)+B01(4) | B23(4) | B45(4) | B67(4).
// ---------------------------------------------------------------------------
__global__ __launch_bounds__(512, 2) void qkv_gemm_kernel(
    const bf16* __restrict__ xb, const bf16* __restrict__ wqkvb,
    const float* __restrict__ bias,
    bf16* __restrict__ qh, bf16* __restrict__ kh, bf16* __restrict__ vT)
{
    __shared__ bf16 lds[8 * 8192];        // 128 KB, 8 slots of 16 KB
    const int tid = threadIdx.x;
    const int bn = blockIdx.x, bm = blockIdx.y;
    const int lane = tid & 63, quad = lane >> 4, lcol = lane & 15;
    const int wave = tid >> 6;
    const int wm = wave >> 1;             // 0..3: rows 64*wm .. +64
    const int wn = wave & 1;              // 0..1: cols 128*wn .. +128
    const int swz = lcol & 7;

    // staging: thread covers (row sr + 64*l, chunk sc) of a 128-row half
    const int sr = tid >> 3, sc = tid & 7;
    const bf16* ga = xb    + (size_t)(bm * 256 + sr) * D_ + ((sc ^ (sr & 7)) << 3);
    const bf16* gb = wqkvb + (size_t)(bn * 256 + sr) * D_ + ((sc ^ (sr & 7)) << 3);
    bf16* ldst = lds + tid * 8;

    auto stage = [&](int t, int kind) {   // one 16KB half = 2 glds16/thread
        const bf16* g = ((kind & 2) ? gb : ga) +
                        (size_t)(kind & 1) * 128 * D_ + t * 64;
        bf16* d = ldst + (((t & 1) * 4 + kind) & 7) * 8192;
        glds16(g, d);
        glds16(g + (size_t)64 * D_, d + 4096);
    };

    f32x4 acc[4][8];
    const f32x4 z = {0.f, 0.f, 0.f, 0.f};
#pragma unroll
    for (int i = 0; i < 4; i++)
#pragma unroll
        for (int j = 0; j < 8; j++) acc[i][j] = z;

    const int NT = D_ / 64;               // 32 K-tiles

    // prologue: A(0), B(0), A(1)  -> 12 loads in flight
    stage(0, 0); stage(0, 1); stage(0, 2); stage(0, 3);
    stage(1, 0); stage(1, 1);

#define QKV_TILE(t, par, LASTV)                                                \
    {                                                                          \
        if (LASTV) asm volatile("s_waitcnt vmcnt(0)" ::: "memory");            \
        else       asm volatile("s_waitcnt vmcnt(4)" ::: "memory");            \
        __builtin_amdgcn_s_barrier();                                          \
        __builtin_amdgcn_sched_barrier(0);                                     \
        if ((t) + 1 < NT) { stage((t) + 1, 2); stage((t) + 1, 3); }            \
        const bf16* sA = lds + ((par) + (wm >> 1)) * 8192 + ((wm & 1) * 64) * 64; \
        const bf16* sB = lds + ((par) + 2 + wn) * 8192;                        \
        bf16x8 af[4][2];                                                       \
        _Pragma("unroll")                                                      \
        for (int i = 0; i < 4; i++)                                            \
            _Pragma("unroll")                                                  \
            for (int kk = 0; kk < 2; kk++)                                     \
                af[i][kk] = *(const bf16x8*)&sA[(i * 16 + lcol) * 64 +         \
                                                (((kk * 4 + quad) ^ swz) << 3)]; \
        _Pragma("unroll")                                                      \
        for (int jp = 0; jp < 2; jp++) {  /* j-pairs 0-1, 2-3 */               \
            bf16x8 bf[2][2];                                                   \
            _Pragma("unroll")                                                  \
            for (int jj = 0; jj < 2; jj++)                                     \
                _Pragma("unroll")                                              \
                for (int kk = 0; kk < 2; kk++)                                 \
                    bf[jj][kk] = *(const bf16x8*)&sB[((jp * 2 + jj) * 16 + lcol) * 64 + \
                                                     (((kk * 4 + quad) ^ swz) << 3)]; \
            __builtin_amdgcn_s_setprio(1);                                     \
            _Pragma("unroll")                                                  \
            for (int jj = 0; jj < 2; jj++)                                     \
                _Pragma("unroll")                                              \
                for (int kk = 0; kk < 2; kk++)                                 \
                    _Pragma("unroll")                                          \
                    for (int i = 0; i < 4; i++)                                \
                        acc[i][jp * 2 + jj] = __builtin_amdgcn_mfma_f32_16x16x32_bf16( \
                            af[i][kk], bf[jj][kk], acc[i][jp * 2 + jj], 0, 0, 0); \
            __builtin_amdgcn_s_setprio(0);                                     \
        }                                                                      \
        __builtin_amdgcn_s_barrier();     /* pacing: A reads done block-wide */\
        __builtin_amdgcn_sched_barrier(0);                                     \
        if ((t) + 2 < NT) { stage((t) + 2, 0); stage((t) + 2, 1); }            \
        _Pragma("unroll")                                                      \
        for (int jp = 2; jp < 4; jp++) {  /* j-pairs 4-5, 6-7 */               \
            bf16x8 bf[2][2];                                                   \
            _Pragma("unroll")                                                  \
            for (int jj = 0; jj < 2; jj++)                                     \
                _Pragma("unroll")                                              \
                for (int kk = 0; kk < 2; kk++)                                 \
                    bf[jj][kk] = *(const bf16x8*)&sB[((jp * 2 + jj) * 16 + lcol) * 64 + \
                                                     (((kk * 4 + quad) ^ swz) << 3)]; \
            __builtin_amdgcn_s_setprio(1);                                     \
            _Pragma("unroll")                                                  \
            for (int jj = 0; jj < 2; jj++)                                     \
                _Pragma("unroll")                                              \
                for (int kk = 0; kk < 2; kk++)                                 \
                    _Pragma("unroll")                                          \
                    for (int i = 0; i < 4; i++)                                \
                        acc[i][jp * 2 + jj] = __builtin_amdgcn_mfma_f32_16x16x32_bf16( \
                            af[i][kk], bf[jj][kk], acc[i][jp * 2 + jj], 0, 0, 0); \
            __builtin_amdgcn_s_setprio(0);                                     \
        }                                                                      \
    }

    for (int tt = 0; tt < 15; tt++) {
        QKV_TILE(2 * tt, 0, false);
        QKV_TILE(2 * tt + 1, 4, false);
    }
    QKV_TILE(30, 0, false);
    QKV_TILE(31, 4, true);                // final tile: full drain is fine
#undef QKV_TILE

    // ---- epilogue ----
    const int n0 = bn * 256 + wn * 128;   // absolute output column base
    const int part = bn >> 3;             // 0=q 1=k 2=v (256 | 2048 boundaries)
    const int hh = (bn & 7) * 2 + wn;     // head within part
    const int mb0 = bm * 256 + wm * 64;   // 64-aligned, single batch
    const int bb = mb0 >> 11, tb = mb0 & (T_ - 1);

    if (part < 2) {
        bf16* dst = (part == 0) ? qh : kh;
#pragma unroll
        for (int jp = 0; jp < 4; jp++) {
            const int d1 = jp * 16 + lcol;            // 0..63
            const float invf = __expf(-0.14391156831212787f * (float)d1);
            const float b1 = bias[n0 + d1];
            const float b2 = bias[n0 + d1 + 64];
#pragma unroll
            for (int i = 0; i < 4; i++) {
#pragma unroll
                for (int r = 0; r < 4; r++) {
                    const int t = tb + i * 16 + quad * 4 + r;
                    const float x1 = acc[i][jp][r] + b1;       // d1
                    const float x2 = acc[i][jp + 4][r] + b2;   // d1 + 64
                    float s, c;
                    __sincosf((float)t * invf, &s, &c);
                    const size_t rowo = ((size_t)(bb * H_ + hh) * T_ + t) * HD_;
                    dst[rowo + d1]      = (bf16)(x1 * c - x2 * s);
                    dst[rowo + d1 + 64] = (bf16)(x1 * s + x2 * c);
                }
            }
        }
    } else {
        const int bh = bb * H_ + hh;
#pragma unroll
        for (int j = 0; j < 8; j++) {
            const int d = j * 16 + lcol;
            const float bv = bias[n0 + d];
            bf16* vdst = &vT[((size_t)bh * HD_ + d) * T_ + tb];
#pragma unroll
            for (int r = 0; r < 4; r++) {
                union { bf16 hhv[4]; ushort4 u; } pk;
#pragma unroll
                for (int i = 0; i < 4; i++) pk.hhv[i] = (bf16)(acc[i][j][r] + bv);
                // phys(t = i*16 + quad*4 + r) = (quad*4+r)*4 + i
                *(ushort4*)&vdst[(quad * 4 + r) * 4] = pk.u;
            }
        }
    }
}

// ---------------------------------------------------------------------------
// Flash attention (causal), R11 structure (kept): R7 inner loop + uniform
// 64-row tile pairs (qt, 31-qt) -> 33 steps/block, 512 blocks, 2 blocks/CU.
// K+V LDS dbuf via glds16 + XOR swizzle, pi-permuted packed P, no-max
// softmax, diag-only masking, setprio on MFMA clusters. 72 KB LDS.
// ---------------------------------------------------------------------------
__global__ __launch_bounds__(256) void attn_kernel(
    const bf16* __restrict__ qh, const bf16* __restrict__ kh,
    const bf16* __restrict__ vT, bf16* __restrict__ ctx)
{
    __shared__ bf16 lds_k[2][64 * 128];   // [key][d], XOR-swizzled
    __shared__ bf16 lds_v[2][128 * 64];   // [d][phys-key], XOR-swizzled
    __shared__ bf16 lds_p[64 * 64];       // P (phys-key order), wave-private rows
    const int tid = threadIdx.x;
    const int id = blockIdx.x;            // 512 = 32 bh x 16 pairs
    const int bh = id & 31;
    const int qp = id >> 5;               // 0..15
    const int qtA = 31 - qp;              // heavy tile first (16..31)
    const int qtB = qp;                   // light tile (0..15)
    const int ktA = qtA + 1;              // steps for tile A; ktA+(qtB+1)==33
    const int lane = tid & 63, quad = lane >> 4, lcol = lane & 15;
    const int wave = tid >> 6;
    const int wq0 = wave * 16;
    const float scale2 = 0.08838834764831845f * 1.4426950408889634f;
    const int b = bh >> 4, h = bh & 15;

    const bf16* kbase = kh + (size_t)bh * T_ * HD_;
    const bf16* vbase = vT + (size_t)bh * HD_ * T_;

    const int ksrow = tid >> 4;                        // 0..15
    const bf16* kstage = kbase + (size_t)ksrow * HD_ + (((tid & 15) ^ ksrow) << 3);
    const int vsd = tid >> 3;                          // 0..31
    const bf16* vstage = vbase + (size_t)vsd * T_ + (((tid & 7) ^ (vsd & 7)) << 3);

    int qt_cur = qtA;
    int q0 = qtA * 64;

    bf16x8 qf[4];
    auto load_q = [&](int q0_) {
#pragma unroll
        for (int kk = 0; kk < 4; kk++)
            qf[kk] = *(const bf16x8*)&qh[((size_t)bh * T_ + q0_ + wq0 + lcol) * HD_ +
                                         kk * 32 + quad * 8];
    };
    load_q(q0);

    f32x4 o[8];
    const f32x4 z = {0.f, 0.f, 0.f, 0.f};
#pragma unroll
    for (int jd = 0; jd < 8; jd++) o[jd] = z;
    float l_part[4] = {0.f, 0.f, 0.f, 0.f};

    auto do_epilogue = [&](int q0_) {
        float inv_l[4];
#pragma unroll
        for (int r = 0; r < 4; r++) {
            float rs = l_part[r];
#pragma unroll
            for (int off = 1; off < 16; off <<= 1)
                rs += __shfl_xor(rs, off);
            inv_l[r] = 1.0f / rs;
        }
#pragma unroll
        for (int r = 0; r < 4; r++) {
            const int t = q0_ + wq0 + quad * 4 + r;
#pragma unroll
            for (int jd = 0; jd < 8; jd++)
                ctx[((size_t)(b * T_ + t)) * D_ + h * HD_ + jd * 16 + lcol] =
                    (bf16)(o[jd][r] * inv_l[r]);
        }
    };

    // prologue: stage key-tile 0 into buf 0
#pragma unroll
    for (int p = 0; p < 4; p++) {
        glds16(kstage + (size_t)16 * p * HD_, &lds_k[0][tid * 8 + p * 2048]);
        glds16(vstage + (size_t)32 * p * T_, &lds_v[0][tid * 8 + p * 2048]);
    }

    for (int s = 0; s < 33; s++) {
        __syncthreads();                  // stage(s) landed; buf^1 reads done
        if (s + 1 < 33) {                 // prefetch next key-tile (flat seq)
            const int kn = (s + 1 < ktA) ? (s + 1) : (s + 1 - ktA);
            const bf16* ks = kstage + (size_t)kn * 64 * HD_;
            const bf16* vs = vstage + kn * 64;
            bf16* lkd = &lds_k[(s + 1) & 1][tid * 8];
            bf16* lvd = &lds_v[(s + 1) & 1][tid * 8];
#pragma unroll
            for (int p = 0; p < 4; p++) {
                glds16(ks + (size_t)16 * p * HD_, lkd + p * 2048);
                glds16(vs + (size_t)32 * p * T_, lvd + p * 2048);
            }
        }
        if (s == ktA) {                   // tile switch A -> B (block-uniform)
            do_epilogue(q0);
            qt_cur = qtB;
            q0 = qtB * 64;
            load_q(q0);
#pragma unroll
            for (int jd = 0; jd < 8; jd++) o[jd] = z;
#pragma unroll
            for (int r = 0; r < 4; r++) l_part[r] = 0.f;
        }
        const int kt = (s < ktA) ? s : (s - ktA);
        const bf16* lk = lds_k[s & 1];
        const bf16* lv = lds_v[s & 1];

        // ---- QK^T: K B-fragments from swizzled LDS ----
        f32x4 s_acc[4];
#pragma unroll
        for (int j = 0; j < 4; j++) s_acc[j] = z;
        __builtin_amdgcn_s_setprio(1);
#pragma unroll
        for (int kk = 0; kk < 4; kk++) {
#pragma unroll
            for (int j = 0; j < 4; j++) {
                const bf16x8 bk = *(const bf16x8*)&lk[(j * 16 + lcol) * 128 +
                                        (((kk * 4 + quad) ^ lcol) << 3)];
                s_acc[j] = __builtin_amdgcn_mfma_f32_16x16x32_bf16(qf[kk], bk, s_acc[j], 0, 0, 0);
            }
        }
        __builtin_amdgcn_s_setprio(0);

        // ---- no-max softmax; packed P store in pi-permuted key order ----
        const bool diag = (kt == qt_cur);
#pragma unroll
        for (int r = 0; r < 4; r++) {
            const int prow = wq0 + quad * 4 + r;      // P row (q-local)
            const int qrow = q0 + prow;               // global q row
            union { bf16 hh[4]; ushort4 u; } pk;
            float lp = 0.f;
#pragma unroll
            for (int j = 0; j < 4; j++) {
                float p = exp2f(fmaf(s_acc[j][r], scale2, -16.0f));
                if (diag) {
                    const int kcol = kt * 64 + j * 16 + lcol;
                    p = (kcol > qrow) ? 0.f : p;
                }
                lp += p;
                pk.hh[j] = (bf16)p;      // phys key = lcol*4 + j
            }
            l_part[r] += lp;
            *(ushort4*)&lds_p[prow * 64 + ((lcol * 4) ^ ((prow & 7) << 3))] = pk.u;
        }

        // ---- PV: P and V both from LDS (short, stall-free path) ----
#pragma unroll
        for (int kk2 = 0; kk2 < 2; kk2++) {
            const int prow = wq0 + lcol;
            const bf16x8 pf = *(const bf16x8*)&lds_p[prow * 64 +
                                  ((kk2 * 32 + quad * 8) ^ ((lcol & 7) << 3))];
            bf16x8 vf[8];
#pragma unroll
            for (int jd = 0; jd < 8; jd++) {
                const int d = jd * 16 + lcol;
                vf[jd] = *(const bf16x8*)&lv[d * 64 +
                              (((kk2 * 4 + quad) ^ (lcol & 7)) << 3)];
            }
            __builtin_amdgcn_s_setprio(1);
#pragma unroll
            for (int jd = 0; jd < 8; jd++)
                o[jd] = __builtin_amdgcn_mfma_f32_16x16x32_bf16(pf, vf[jd], o[jd], 0, 0, 0);
            __builtin_amdgcn_s_setprio(0);
        }
    }

    do_epilogue(q0);                      // tile B epilogue
}

// ---------------------------------------------------------------------------
// Output projection: out = ctx @ Wo^T + bo  (bf16 x bf16 -> fp32 out)
// ---------------------------------------------------------------------------
__global__ __launch_bounds__(256) void proj_gemm_kernel(
    const bf16* __restrict__ ctx, const bf16* __restrict__ wob,
    const float* __restrict__ bias, float* __restrict__ out)
{
    __shared__ bf16 lds_a[128 * 64];
    __shared__ bf16 lds_b[128 * 64];
    const int tid = threadIdx.x;
    const int bm = blockIdx.y, bn = blockIdx.x;
    const int lane = tid & 63, quad = lane >> 4, lcol = lane & 15;
    const int wave = tid >> 6;
    const int wm = (wave >> 1) * 64, wn2 = (wave & 1) * 32;

    f32x4 acc[4][4];
    const f32x4 z = {0.f, 0.f, 0.f, 0.f};
#pragma unroll
    for (int i = 0; i < 4; i++)
#pragma unroll
        for (int j = 0; j < 4; j++) acc[i][j] = z;

    gemm_core_glds(ctx, wob, D_, bm, bn, tid, acc, lds_a, lds_b);

    const int n0 = bn * 128;
#pragma unroll
    for (int i = 0; i < 4; i++) {
#pragma unroll
        for (int j = 0; j < 4; j++) {
            const int n = n0 + wn2 + (j & 1) * 16 + (j >> 1) * 64 + lcol;
            const float bv = bias[n];
#pragma unroll
            for (int r = 0; r < 4; r++) {
                const int m = bm * 128 + wm + i * 16 + quad * 4 + r;
                out[(size_t)m * D_ + n] = acc[i][j][r] + bv;
            }
        }
    }
}

extern "C" void kernel_launch(void* const* d_in, const int* in_sizes, int n_in,
                              void* d_out, int out_size, void* d_ws, size_t ws_size,
                              hipStream_t stream)
{
    const float* x    = (const float*)d_in[0];
    const float* Wqkv = (const float*)d_in[1];
    const float* bqkv = (const float*)d_in[2];
    const float* Wo   = (const float*)d_in[3];
    const float* bo   = (const float*)d_in[4];
    // d_in[5] = mask — causal, computed analytically in-kernel.
    float* out = (float*)d_out;

    const size_t HT = (size_t)B_ * H_ * T_ * HD_;   // 8,388,608 elems
    // d_ws (67.1 MB, proven size): [xb|ctx][qh|wob][kh][vT]
    bf16* xb   = (bf16*)d_ws;
    bf16* qh   = xb + HT;
    bf16* kh   = qh + HT;
    bf16* vT   = kh + HT;
    bf16* ctx  = xb;             // xb dead after qkv gemm
    bf16* wob  = qh;             // qh dead after attn
    // d_out (33.55 MB fp32): holds bf16 Wqkv (25.2 MB) until proj overwrites
    bf16* wqkvb = (bf16*)d_out;

    // 1) fp32 -> bf16 pre-convert of x and Wqkv
    convert_xw_kernel<<<2560, 256, 0, stream>>>(x, Wqkv, xb, wqkvb);
    // 2) QKV projection + fused RoPE + head scatter:
    //    256^2 8-phase counted-vmcnt GEMM, 384 blocks x 512 threads
    qkv_gemm_kernel<<<dim3(24, 16), 512, 0, stream>>>(xb, wqkvb, bqkv, qh, kh, vT);
    // 3) causal flash attention -> ctx (R11: uniform 64-row tile pairs)
    attn_kernel<<<512, 256, 0, stream>>>(qh, kh, vT, ctx);
    // 4) Wo -> bf16 into dead qh region
    convert_wo_kernel<<<1024, 256, 0, stream>>>(Wo, wob);
    // 5) output projection -> fp32 out (overwrites wqkvb region)
    proj_gemm_kernel<<<dim3(16, 32), 256, 0, stream>>>(ctx, wob, bo, out);
}

// Round 8
// 365.248 us; speedup vs baseline: 1.0065x; 1.0065x over previous
//
#include <hip/hip_runtime.h>
#include <hip/hip_bf16.h>
#include <cstdint>

typedef __bf16 bf16;
typedef __bf16 bf16x8 __attribute__((ext_vector_type(8)));
typedef float  f32x4  __attribute__((ext_vector_type(4)));

#define B_   2
#define T_   2048
#define D_   2048
#define H_   16
#define HD_  128

// async global->LDS, 16 B per lane (m97: the 874 TF enabler).
// LDS dest must be wave-uniform base + lane*16 -> lanes stay contiguous in
// physical-slot order; we permute the GLOBAL side per-lane for XOR swizzles.
typedef __attribute__((address_space(3))) void       lds_void;
typedef __attribute__((address_space(1))) const void gbl_void;
__device__ __forceinline__ void glds16(const bf16* g, bf16* l) {
    __builtin_amdgcn_global_load_lds((gbl_void*)g, (lds_void*)l, 16, 0, 0);
}

// ---------------------------------------------------------------------------
// fp32 -> bf16 pre-convert (grid-stride, float4 -> 4x bf16 pack)
// ---------------------------------------------------------------------------
__device__ __forceinline__ ushort4 cvt4(const float4 v) {
    union { bf16 h[4]; ushort4 u; } pk;
    pk.h[0] = (bf16)v.x; pk.h[1] = (bf16)v.y;
    pk.h[2] = (bf16)v.z; pk.h[3] = (bf16)v.w;
    return pk.u;
}

__global__ __launch_bounds__(256) void convert_xw_kernel(
    const float* __restrict__ x, const float* __restrict__ wqkv,
    bf16* __restrict__ xb, bf16* __restrict__ wqkvb)
{
    const int NX = (B_ * T_ * D_) / 4;          // 2,097,152 float4
    const int NT = NX + (3 * D_ * D_) / 4;      // + 3,145,728
    for (int g = blockIdx.x * blockDim.x + threadIdx.x; g < NT;
         g += gridDim.x * blockDim.x) {
        if (g < NX) ((ushort4*)xb)[g]      = cvt4(((const float4*)x)[g]);
        else        ((ushort4*)wqkvb)[g-NX] = cvt4(((const float4*)wqkv)[g-NX]);
    }
}

__global__ __launch_bounds__(256) void convert_wo_kernel(
    const float* __restrict__ wo, bf16* __restrict__ wob)
{
    const int N = (D_ * D_) / 4;                // 1,048,576 float4
    for (int g = blockIdx.x * blockDim.x + threadIdx.x; g < N;
         g += gridDim.x * blockDim.x)
        ((ushort4*)wob)[g] = cvt4(((const float4*)wo)[g]);
}

// ---------------------------------------------------------------------------
// m97-style NT-GEMM core with XOR-swizzled LDS: C[128x128], A[M][K], W[N][K]
// (used by proj_gemm)
// ---------------------------------------------------------------------------
__device__ __forceinline__ void gemm_core_glds(
    const bf16* __restrict__ A, const bf16* __restrict__ W, int K,
    int bm, int bn, int tid, f32x4 (&acc)[4][4],
    bf16* lds_a, bf16* lds_b)
{
    const int lane = tid & 63, quad = lane >> 4, lcol = lane & 15;
    const int wave = tid >> 6;
    const int wm = (wave >> 1) * 64, wn2 = (wave & 1) * 32;
    const int sw = lcol & 7;                          // read-side swizzle key
    const int sr = tid >> 3, pc = tid & 7;            // staging row / physical chunk
    const int sc = (pc ^ (sr & 7)) * 8;               // logical col group fetched
    const bf16* abase = A + (size_t)(bm * 128 + sr) * K + sc;
    const bf16* bbase = W + (size_t)(bn * 128 + sr) * K + sc;
    bf16* la = lds_a + sr * 64 + pc * 8;              // = lds_a + tid*8 elems
    bf16* lb = lds_b + sr * 64 + pc * 8;

    for (int k0 = 0; k0 < K; k0 += 64) {
        __syncthreads();
#pragma unroll
        for (int p = 0; p < 4; p++) {                 // (sr+32p)&7 == sr&7
            glds16(abase + k0 + (size_t)32 * p * K, la + 2048 * p);
            glds16(bbase + k0 + (size_t)32 * p * K, lb + 2048 * p);
        }
        __syncthreads();
#pragma unroll
        for (int kk = 0; kk < 2; kk++) {
            bf16x8 af[4], bfr[4];
#pragma unroll
            for (int i = 0; i < 4; i++)
                af[i] = *(const bf16x8*)&lds_a[(wm + i * 16 + lcol) * 64 +
                                               (((kk * 4 + quad) ^ sw) * 8)];
#pragma unroll
            for (int j = 0; j < 4; j++) {
                const int row = wn2 + (j & 1) * 16 + (j >> 1) * 64 + lcol;
                bfr[j] = *(const bf16x8*)&lds_b[row * 64 +
                                                (((kk * 4 + quad) ^ sw) * 8)];
            }
#pragma unroll
            for (int i = 0; i < 4; i++)
#pragma unroll
                for (int j = 0; j < 4; j++)
                    acc[i][j] = __builtin_amdgcn_mfma_f32_16x16x32_bf16(af[i], bfr[j], acc[i][j], 0, 0, 0);
        }
    }
}

// ---------------------------------------------------------------------------
// QKV projection, R13 = R12 structure with the VGPR cap FIXED.
// R12 post-mortem: launch_bounds(512,2) capped VGPR at 128 (empirical rule:
// cap ~ 256/min_waves_per_EU; R6's (256,4)->64 confirms) but acc[4][8] alone
// is 128 VGPRs -> accumulator spilled to scratch (WRITE_SIZE +17.5MB),
// MfmaUtil pinned at 37%. R13: launch_bounds(512,1) -> cap 256; budget
// acc 128 + af 32 + bf 16 + addr ~40 = ~220, fits. Schedule unchanged:
//
// 256x256 tile, BK=64, 8 waves (4M x 2N, per-wave C=64x128 so RoPE pairs
// (d, d+64) are register-local). LDS = 8 x 16KB slots, XOR-swizzled.
// Counted-vmcnt pipeline (T3+T4): stage B(t+1) post-boundary, A(t+2) after
// the mid-tile pacing barrier; boundary wait = vmcnt(4) (A(t+1) loads stay
// in flight ACROSS the barrier); drain to 0 only at the final tile.
// ---------------------------------------------------------------------------
__global__ __launch_bounds__(512, 1) void qkv_gemm_kernel(
    const bf16* __restrict__ xb, const bf16* __restrict__ wqkvb,
    const float* __restrict__ bias,
    bf16* __restrict__ qh, bf16* __restrict__ kh, bf16* __restrict__ vT)
{
    __shared__ bf16 lds[8 * 8192];        // 128 KB, 8 slots of 16 KB
    const int tid = threadIdx.x;
    const int bn = blockIdx.x, bm = blockIdx.y;
    const int lane = tid & 63, quad = lane >> 4, lcol = lane & 15;
    const int wave = tid >> 6;
    const int wm = wave >> 1;             // 0..3: rows 64*wm .. +64
    const int wn = wave & 1;              // 0..1: cols 128*wn .. +128
    const int swz = lcol & 7;

    // staging: thread covers (row sr + 64*l, chunk sc) of a 128-row half
    const int sr = tid >> 3, sc = tid & 7;
    const bf16* ga = xb    + (size_t)(bm * 256 + sr) * D_ + ((sc ^ (sr & 7)) << 3);
    const bf16* gb = wqkvb + (size_t)(bn * 256 + sr) * D_ + ((sc ^ (sr & 7)) << 3);
    bf16* ldst = lds + tid * 8;

    auto stage = [&](int t, int kind) {   // one 16KB half = 2 glds16/thread
        const bf16* g = ((kind & 2) ? gb : ga) +
                        (size_t)(kind & 1) * 128 * D_ + t * 64;
        bf16* d = ldst + (((t & 1) * 4 + kind) & 7) * 8192;
        glds16(g, d);
        glds16(g + (size_t)64 * D_, d + 4096);
    };

    f32x4 acc[4][8];
    const f32x4 z = {0.f, 0.f, 0.f, 0.f};
#pragma unroll
    for (int i = 0; i < 4; i++)
#pragma unroll
        for (int j = 0; j < 8; j++) acc[i][j] = z;

    const int NT = D_ / 64;               // 32 K-tiles

    // prologue: A(0), B(0), A(1)  -> 12 loads in flight
    stage(0, 0); stage(0, 1); stage(0, 2); stage(0, 3);
    stage(1, 0); stage(1, 1);

#define QKV_TILE(t, par, LASTV)                                                \
    {                                                                          \
        if (LASTV) asm volatile("s_waitcnt vmcnt(0)" ::: "memory");            \
        else       asm volatile("s_waitcnt vmcnt(4)" ::: "memory");            \
        __builtin_amdgcn_s_barrier();                                          \
        __builtin_amdgcn_sched_barrier(0);                                     \
        if ((t) + 1 < NT) { stage((t) + 1, 2); stage((t) + 1, 3); }            \
        const bf16* sA = lds + ((par) + (wm >> 1)) * 8192 + ((wm & 1) * 64) * 64; \
        const bf16* sB = lds + ((par) + 2 + wn) * 8192;                        \
        bf16x8 af[4][2];                                                       \
        _Pragma("unroll")                                                      \
        for (int i = 0; i < 4; i++)                                            \
            _Pragma("unroll")                                                  \
            for (int kk = 0; kk < 2; kk++)                                     \
                af[i][kk] = *(const bf16x8*)&sA[(i * 16 + lcol) * 64 +         \
                                                (((kk * 4 + quad) ^ swz) << 3)]; \
        _Pragma("unroll")                                                      \
        for (int jp = 0; jp < 2; jp++) {  /* j-pairs 0-1, 2-3 */               \
            bf16x8 bf[2][2];                                                   \
            _Pragma("unroll")                                                  \
            for (int jj = 0; jj < 2; jj++)                                     \
                _Pragma("unroll")                                              \
                for (int kk = 0; kk < 2; kk++)                                 \
                    bf[jj][kk] = *(const bf16x8*)&sB[((jp * 2 + jj) * 16 + lcol) * 64 + \
                                                     (((kk * 4 + quad) ^ swz) << 3)]; \
            __builtin_amdgcn_s_setprio(1);                                     \
            _Pragma("unroll")                                                  \
            for (int jj = 0; jj < 2; jj++)                                     \
                _Pragma("unroll")                                              \
                for (int kk = 0; kk < 2; kk++)                                 \
                    _Pragma("unroll")                                          \
                    for (int i = 0; i < 4; i++)                                \
                        acc[i][jp * 2 + jj] = __builtin_amdgcn_mfma_f32_16x16x32_bf16( \
                            af[i][kk], bf[jj][kk], acc[i][jp * 2 + jj], 0, 0, 0); \
            __builtin_amdgcn_s_setprio(0);                                     \
        }                                                                      \
        __builtin_amdgcn_s_barrier();     /* pacing: A reads done block-wide */\
        __builtin_amdgcn_sched_barrier(0);                                     \
        if ((t) + 2 < NT) { stage((t) + 2, 0); stage((t) + 2, 1); }            \
        _Pragma("unroll")                                                      \
        for (int jp = 2; jp < 4; jp++) {  /* j-pairs 4-5, 6-7 */               \
            bf16x8 bf[2][2];                                                   \
            _Pragma("unroll")                                                  \
            for (int jj = 0; jj < 2; jj++)                                     \
                _Pragma("unroll")                                              \
                for (int kk = 0; kk < 2; kk++)                                 \
                    bf[jj][kk] = *(const bf16x8*)&sB[((jp * 2 + jj) * 16 + lcol) * 64 + \
                                                     (((kk * 4 + quad) ^ swz) << 3)]; \
            __builtin_amdgcn_s_setprio(1);                                     \
            _Pragma("unroll")                                                  \
            for (int jj = 0; jj < 2; jj++)                                     \
                _Pragma("unroll")                                              \
                for (int kk = 0; kk < 2; kk++)                                 \
                    _Pragma("unroll")                                          \
                    for (int i = 0; i < 4; i++)                                \
                        acc[i][jp * 2 + jj] = __builtin_amdgcn_mfma_f32_16x16x32_bf16( \
                            af[i][kk], bf[jj][kk], acc[i][jp * 2 + jj], 0, 0, 0); \
            __builtin_amdgcn_s_setprio(0);                                     \
        }                                                                      \
    }

    for (int tt = 0; tt < 15; tt++) {
        QKV_TILE(2 * tt, 0, false);
        QKV_TILE(2 * tt + 1, 4, false);
    }
    QKV_TILE(30, 0, false);
    QKV_TILE(31, 4, true);                // final tile: full drain is fine
#undef QKV_TILE

    // ---- epilogue ----
    const int n0 = bn * 256 + wn * 128;   // absolute output column base
    const int part = bn >> 3;             // 0=q 1=k 2=v (256 | 2048 boundaries)
    const int hh = (bn & 7) * 2 + wn;     // head within part
    const int mb0 = bm * 256 + wm * 64;   // 64-aligned, single batch
    const int bb = mb0 >> 11, tb = mb0 & (T_ - 1);

    if (part < 2) {
        bf16* dst = (part == 0) ? qh : kh;
#pragma unroll
        for (int jp = 0; jp < 4; jp++) {
            const int d1 = jp * 16 + lcol;            // 0..63
            const float invf = __expf(-0.14391156831212787f * (float)d1);
            const float b1 = bias[n0 + d1];
            const float b2 = bias[n0 + d1 + 64];
#pragma unroll
            for (int i = 0; i < 4; i++) {
#pragma unroll
                for (int r = 0; r < 4; r++) {
                    const int t = tb + i * 16 + quad * 4 + r;
                    const float x1 = acc[i][jp][r] + b1;       // d1
                    const float x2 = acc[i][jp + 4][r] + b2;   // d1 + 64
                    float s, c;
                    __sincosf((float)t * invf, &s, &c);
                    const size_t rowo = ((size_t)(bb * H_ + hh) * T_ + t) * HD_;
                    dst[rowo + d1]      = (bf16)(x1 * c - x2 * s);
                    dst[rowo + d1 + 64] = (bf16)(x1 * s + x2 * c);
                }
            }
        }
    } else {
        const int bh = bb * H_ + hh;
#pragma unroll
        for (int j = 0; j < 8; j++) {
            const int d = j * 16 + lcol;
            const float bv = bias[n0 + d];
            bf16* vdst = &vT[((size_t)bh * HD_ + d) * T_ + tb];
#pragma unroll
            for (int r = 0; r < 4; r++) {
                union { bf16 hhv[4]; ushort4 u; } pk;
#pragma unroll
                for (int i = 0; i < 4; i++) pk.hhv[i] = (bf16)(acc[i][j][r] + bv);
                // phys(t = i*16 + quad*4 + r) = (quad*4+r)*4 + i
                *(ushort4*)&vdst[(quad * 4 + r) * 4] = pk.u;
            }
        }
    }
}

// ---------------------------------------------------------------------------
// Flash attention (causal), R11 structure (kept): R7 inner loop + uniform
// 64-row tile pairs (qt, 31-qt) -> 33 steps/block, 512 blocks, 2 blocks/CU.
// K+V LDS dbuf via glds16 + XOR swizzle, pi-permuted packed P, no-max
// softmax, diag-only masking, setprio on MFMA clusters. 72 KB LDS.
// ---------------------------------------------------------------------------
__global__ __launch_bounds__(256) void attn_kernel(
    const bf16* __restrict__ qh, const bf16* __restrict__ kh,
    const bf16* __restrict__ vT, bf16* __restrict__ ctx)
{
    __shared__ bf16 lds_k[2][64 * 128];   // [key][d], XOR-swizzled
    __shared__ bf16 lds_v[2][128 * 64];   // [d][phys-key], XOR-swizzled
    __shared__ bf16 lds_p[64 * 64];       // P (phys-key order), wave-private rows
    const int tid = threadIdx.x;
    const int id = blockIdx.x;            // 512 = 32 bh x 16 pairs
    const int bh = id & 31;
    const int qp = id >> 5;               // 0..15
    const int qtA = 31 - qp;              // heavy tile first (16..31)
    const int qtB = qp;                   // light tile (0..15)
    const int ktA = qtA + 1;              // steps for tile A; ktA+(qtB+1)==33
    const int lane = tid & 63, quad = lane >> 4, lcol = lane & 15;
    const int wave = tid >> 6;
    const int wq0 = wave * 16;
    const float scale2 = 0.08838834764831845f * 1.4426950408889634f;
    const int b = bh >> 4, h = bh & 15;

    const bf16* kbase = kh + (size_t)bh * T_ * HD_;
    const bf16* vbase = vT + (size_t)bh * HD_ * T_;

    const int ksrow = tid >> 4;                        // 0..15
    const bf16* kstage = kbase + (size_t)ksrow * HD_ + (((tid & 15) ^ ksrow) << 3);
    const int vsd = tid >> 3;                          // 0..31
    const bf16* vstage = vbase + (size_t)vsd * T_ + (((tid & 7) ^ (vsd & 7)) << 3);

    int qt_cur = qtA;
    int q0 = qtA * 64;

    bf16x8 qf[4];
    auto load_q = [&](int q0_) {
#pragma unroll
        for (int kk = 0; kk < 4; kk++)
            qf[kk] = *(const bf16x8*)&qh[((size_t)bh * T_ + q0_ + wq0 + lcol) * HD_ +
                                         kk * 32 + quad * 8];
    };
    load_q(q0);

    f32x4 o[8];
    const f32x4 z = {0.f, 0.f, 0.f, 0.f};
#pragma unroll
    for (int jd = 0; jd < 8; jd++) o[jd] = z;
    float l_part[4] = {0.f, 0.f, 0.f, 0.f};

    auto do_epilogue = [&](int q0_) {
        float inv_l[4];
#pragma unroll
        for (int r = 0; r < 4; r++) {
            float rs = l_part[r];
#pragma unroll
            for (int off = 1; off < 16; off <<= 1)
                rs += __shfl_xor(rs, off);
            inv_l[r] = 1.0f / rs;
        }
#pragma unroll
        for (int r = 0; r < 4; r++) {
            const int t = q0_ + wq0 + quad * 4 + r;
#pragma unroll
            for (int jd = 0; jd < 8; jd++)
                ctx[((size_t)(b * T_ + t)) * D_ + h * HD_ + jd * 16 + lcol] =
                    (bf16)(o[jd][r] * inv_l[r]);
        }
    };

    // prologue: stage key-tile 0 into buf 0
#pragma unroll
    for (int p = 0; p < 4; p++) {
        glds16(kstage + (size_t)16 * p * HD_, &lds_k[0][tid * 8 + p * 2048]);
        glds16(vstage + (size_t)32 * p * T_, &lds_v[0][tid * 8 + p * 2048]);
    }

    for (int s = 0; s < 33; s++) {
        __syncthreads();                  // stage(s) landed; buf^1 reads done
        if (s + 1 < 33) {                 // prefetch next key-tile (flat seq)
            const int kn = (s + 1 < ktA) ? (s + 1) : (s + 1 - ktA);
            const bf16* ks = kstage + (size_t)kn * 64 * HD_;
            const bf16* vs = vstage + kn * 64;
            bf16* lkd = &lds_k[(s + 1) & 1][tid * 8];
            bf16* lvd = &lds_v[(s + 1) & 1][tid * 8];
#pragma unroll
            for (int p = 0; p < 4; p++) {
                glds16(ks + (size_t)16 * p * HD_, lkd + p * 2048);
                glds16(vs + (size_t)32 * p * T_, lvd + p * 2048);
            }
        }
        if (s == ktA) {                   // tile switch A -> B (block-uniform)
            do_epilogue(q0);
            qt_cur = qtB;
            q0 = qtB * 64;
            load_q(q0);
#pragma unroll
            for (int jd = 0; jd < 8; jd++) o[jd] = z;
#pragma unroll
            for (int r = 0; r < 4; r++) l_part[r] = 0.f;
        }
        const int kt = (s < ktA) ? s : (s - ktA);
        const bf16* lk = lds_k[s & 1];
        const bf16* lv = lds_v[s & 1];

        // ---- QK^T: K B-fragments from swizzled LDS ----
        f32x4 s_acc[4];
#pragma unroll
        for (int j = 0; j < 4; j++) s_acc[j] = z;
        __builtin_amdgcn_s_setprio(1);
#pragma unroll
        for (int kk = 0; kk < 4; kk++) {
#pragma unroll
            for (int j = 0; j < 4; j++) {
                const bf16x8 bk = *(const bf16x8*)&lk[(j * 16 + lcol) * 128 +
                                        (((kk * 4 + quad) ^ lcol) << 3)];
                s_acc[j] = __builtin_amdgcn_mfma_f32_16x16x32_bf16(qf[kk], bk, s_acc[j], 0, 0, 0);
            }
        }
        __builtin_amdgcn_s_setprio(0);

        // ---- no-max softmax; packed P store in pi-permuted key order ----
        const bool diag = (kt == qt_cur);
#pragma unroll
        for (int r = 0; r < 4; r++) {
            const int prow = wq0 + quad * 4 + r;      // P row (q-local)
            const int qrow = q0 + prow;               // global q row
            union { bf16 hh[4]; ushort4 u; } pk;
            float lp = 0.f;
#pragma unroll
            for (int j = 0; j < 4; j++) {
                float p = exp2f(fmaf(s_acc[j][r], scale2, -16.0f));
                if (diag) {
                    const int kcol = kt * 64 + j * 16 + lcol;
                    p = (kcol > qrow) ? 0.f : p;
                }
                lp += p;
                pk.hh[j] = (bf16)p;      // phys key = lcol*4 + j
            }
            l_part[r] += lp;
            *(ushort4*)&lds_p[prow * 64 + ((lcol * 4) ^ ((prow & 7) << 3))] = pk.u;
        }

        // ---- PV: P and V both from LDS (short, stall-free path) ----
#pragma unroll
        for (int kk2 = 0; kk2 < 2; kk2++) {
            const int prow = wq0 + lcol;
            const bf16x8 pf = *(const bf16x8*)&lds_p[prow * 64 +
                                  ((kk2 * 32 + quad * 8) ^ ((lcol & 7) << 3))];
            bf16x8 vf[8];
#pragma unroll
            for (int jd = 0; jd < 8; jd++) {
                const int d = jd * 16 + lcol;
                vf[jd] = *(const bf16x8*)&lv[d * 64 +
                              (((kk2 * 4 + quad) ^ (lcol & 7)) << 3)];
            }
            __builtin_amdgcn_s_setprio(1);
#pragma unroll
            for (int jd = 0; jd < 8; jd++)
                o[jd] = __builtin_amdgcn_mfma_f32_16x16x32_bf16(pf, vf[jd], o[jd], 0, 0, 0);
            __builtin_amdgcn_s_setprio(0);
        }
    }

    do_epilogue(q0);                      // tile B epilogue
}

// ---------------------------------------------------------------------------
// Output projection: out = ctx @ Wo^T + bo  (bf16 x bf16 -> fp32 out)
// ---------------------------------------------------------------------------
__global__ __launch_bounds__(256) void proj_gemm_kernel(
    const bf16* __restrict__ ctx, const bf16* __restrict__ wob,
    const float* __restrict__ bias, float* __restrict__ out)
{
    __shared__ bf16 lds_a[128 * 64];
    __shared__ bf16 lds_b[128 * 64];
    const int tid = threadIdx.x;
    const int bm = blockIdx.y, bn = blockIdx.x;
    const int lane = tid & 63, quad = lane >> 4, lcol = lane & 15;
    const int wave = tid >> 6;
    const int wm = (wave >> 1) * 64, wn2 = (wave & 1) * 32;

    f32x4 acc[4][4];
    const f32x4 z = {0.f, 0.f, 0.f, 0.f};
#pragma unroll
    for (int i = 0; i < 4; i++)
#pragma unroll
        for (int j = 0; j < 4; j++) acc[i][j] = z;

    gemm_core_glds(ctx, wob, D_, bm, bn, tid, acc, lds_a, lds_b);

    const int n0 = bn * 128;
#pragma unroll
    for (int i = 0; i < 4; i++) {
#pragma unroll
        for (int j = 0; j < 4; j++) {
            const int n = n0 + wn2 + (j & 1) * 16 + (j >> 1) * 64 + lcol;
            const float bv = bias[n];
#pragma unroll
            for (int r = 0; r < 4; r++) {
                const int m = bm * 128 + wm + i * 16 + quad * 4 + r;
                out[(size_t)m * D_ + n] = acc[i][j][r] + bv;
            }
        }
    }
}

extern "C" void kernel_launch(void* const* d_in, const int* in_sizes, int n_in,
                              void* d_out, int out_size, void* d_ws, size_t ws_size,
                              hipStream_t stream)
{
    const float* x    = (const float*)d_in[0];
    const float* Wqkv = (const float*)d_in[1];
    const float* bqkv = (const float*)d_in[2];
    const float* Wo   = (const float*)d_in[3];
    const float* bo   = (const float*)d_in[4];
    // d_in[5] = mask — causal, computed analytically in-kernel.
    float* out = (float*)d_out;

    const size_t HT = (size_t)B_ * H_ * T_ * HD_;   // 8,388,608 elems
    // d_ws (67.1 MB, proven size): [xb|ctx][qh|wob][kh][vT]
    bf16* xb   = (bf16*)d_ws;
    bf16* qh   = xb + HT;
    bf16* kh   = qh + HT;
    bf16* vT   = kh + HT;
    bf16* ctx  = xb;             // xb dead after qkv gemm
    bf16* wob  = qh;             // qh dead after attn
    // d_out (33.55 MB fp32): holds bf16 Wqkv (25.2 MB) until proj overwrites
    bf16* wqkvb = (bf16*)d_out;

    // 1) fp32 -> bf16 pre-convert of x and Wqkv
    convert_xw_kernel<<<2560, 256, 0, stream>>>(x, Wqkv, xb, wqkvb);
    // 2) QKV projection + fused RoPE + head scatter:
    //    256^2 counted-vmcnt GEMM, 384 blocks x 512 threads, VGPR cap 256
    qkv_gemm_kernel<<<dim3(24, 16), 512, 0, stream>>>(xb, wqkvb, bqkv, qh, kh, vT);
    // 3) causal flash attention -> ctx (R11: uniform 64-row tile pairs)
    attn_kernel<<<512, 256, 0, stream>>>(qh, kh, vT, ctx);
    // 4) Wo -> bf16 into dead qh region
    convert_wo_kernel<<<1024, 256, 0, stream>>>(Wo, wob);
    // 5) output projection -> fp32 out (overwrites wqkvb region)
    proj_gemm_kernel<<<dim3(16, 32), 256, 0, stream>>>(ctx, wob, bo, out);
}

// Round 10
// 359.528 us; speedup vs baseline: 1.0225x; 1.0159x over previous
//
#include <hip/hip_runtime.h>
#include <hip/hip_bf16.h>
#include <cstdint>

typedef __bf16 bf16;
typedef __bf16 bf16x8 __attribute__((ext_vector_type(8)));
typedef float  f32x4  __attribute__((ext_vector_type(4)));

#define B_   2
#define T_   2048
#define D_   2048
#define H_   16
#define HD_  128

typedef __attribute__((address_space(3))) void       lds_void;
typedef __attribute__((address_space(1))) const void gbl_void;
__device__ __forceinline__ void glds16(const bf16* g, bf16* l) {
    __builtin_amdgcn_global_load_lds((gbl_void*)g, (lds_void*)l, 16, 0, 0);
}

// ---------------------------------------------------------------------------
// fp32 -> bf16 pre-convert (grid-stride, float4 -> 4x bf16 pack)
// ---------------------------------------------------------------------------
__device__ __forceinline__ ushort4 cvt4(const float4 v) {
    union { bf16 h[4]; ushort4 u; } pk;
    pk.h[0] = (bf16)v.x; pk.h[1] = (bf16)v.y;
    pk.h[2] = (bf16)v.z; pk.h[3] = (bf16)v.w;
    return pk.u;
}

__global__ __launch_bounds__(256) void convert_xw_kernel(
    const float* __restrict__ x, const float* __restrict__ wqkv,
    bf16* __restrict__ xb, bf16* __restrict__ wqkvb)
{
    const int NX = (B_ * T_ * D_) / 4;
    const int NT = NX + (3 * D_ * D_) / 4;
    for (int g = blockIdx.x * blockDim.x + threadIdx.x; g < NT;
         g += gridDim.x * blockDim.x) {
        if (g < NX) ((ushort4*)xb)[g]      = cvt4(((const float4*)x)[g]);
        else        ((ushort4*)wqkvb)[g-NX] = cvt4(((const float4*)wqkv)[g-NX]);
    }
}

__global__ __launch_bounds__(256) void convert_wo_kernel(
    const float* __restrict__ wo, bf16* __restrict__ wob)
{
    const int N = (D_ * D_) / 4;
    for (int g = blockIdx.x * blockDim.x + threadIdx.x; g < N;
         g += gridDim.x * blockDim.x)
        ((ushort4*)wob)[g] = cvt4(((const float4*)wo)[g]);
}

// ---------------------------------------------------------------------------
// m97-style NT-GEMM core with XOR-swizzled LDS (used by proj_gemm)
// ---------------------------------------------------------------------------
__device__ __forceinline__ void gemm_core_glds(
    const bf16* __restrict__ A, const bf16* __restrict__ W, int K,
    int bm, int bn, int tid, f32x4 (&acc)[4][4],
    bf16* lds_a, bf16* lds_b)
{
    const int lane = tid & 63, quad = lane >> 4, lcol = lane & 15;
    const int wave = tid >> 6;
    const int wm = (wave >> 1) * 64, wn2 = (wave & 1) * 32;
    const int sw = lcol & 7;
    const int sr = tid >> 3, pc = tid & 7;
    const int sc = (pc ^ (sr & 7)) * 8;
    const bf16* abase = A + (size_t)(bm * 128 + sr) * K + sc;
    const bf16* bbase = W + (size_t)(bn * 128 + sr) * K + sc;
    bf16* la = lds_a + sr * 64 + pc * 8;
    bf16* lb = lds_b + sr * 64 + pc * 8;

    for (int k0 = 0; k0 < K; k0 += 64) {
        __syncthreads();
#pragma unroll
        for (int p = 0; p < 4; p++) {
            glds16(abase + k0 + (size_t)32 * p * K, la + 2048 * p);
            glds16(bbase + k0 + (size_t)32 * p * K, lb + 2048 * p);
        }
        __syncthreads();
#pragma unroll
        for (int kk = 0; kk < 2; kk++) {
            bf16x8 af[4], bfr[4];
#pragma unroll
            for (int i = 0; i < 4; i++)
                af[i] = *(const bf16x8*)&lds_a[(wm + i * 16 + lcol) * 64 +
                                               (((kk * 4 + quad) ^ sw) * 8)];
#pragma unroll
            for (int j = 0; j < 4; j++) {
                const int row = wn2 + (j & 1) * 16 + (j >> 1) * 64 + lcol;
                bfr[j] = *(const bf16x8*)&lds_b[row * 64 +
                                                (((kk * 4 + quad) ^ sw) * 8)];
            }
#pragma unroll
            for (int i = 0; i < 4; i++)
#pragma unroll
                for (int j = 0; j < 4; j++)
                    acc[i][j] = __builtin_amdgcn_mfma_f32_16x16x32_bf16(af[i], bfr[j], acc[i][j], 0, 0, 0);
        }
    }
}

// ---------------------------------------------------------------------------
// QKV projection, R15 = R14 fine-phase 256^2 pipeline + issue-order pinning.
// R14 ended in "container failed twice" (no counters). Audit found no barrier
// divergence, no vmcnt deadlock (guards re-derived: 8 outstanding at each
// guard, oldest 4 retired = exactly the next phases' operands), WAR windows
// >= 2 barriers. Only soft spot: compiler could in principle reorder a
// glds16 issue past the inline-asm vmcnt (race, not hang). R15 pins issue
// order with sched_barrier(0) immediately before every counted vmcnt.
// Pre-commit: same failure again => kernel-caused => revert qkv next round.
//
// Schedule (m201-faithful): 4 fine phases per K-tile, each {<=8 ds_read_b128
// for ONE 16-MFMA quadrant, stage 1 halftile (2 glds16), barrier, lgkmcnt(0),
// 16 MFMA (setprio), barrier}. Halftiles by K-half (Ak0,Bk0,Ak1,Bk1; 16KB;
// 8 slots = 128KB). Stage order at tile t: ph0 Ak0(t+1), ph1 Bk0(t+1),
// ph2 Ak1(t+1), ph3 Bk1(t+1); guards vmcnt(4) at ph1 & ph3 only (never 0
// except the peeled final tile). Live frags/phase: af[4]+bfr[4] -> no spill.
// Swizzle: 4 chunks/row, phys = chunk ^ ((row>>1)&3) -> 2-way (free, m136).
// ---------------------------------------------------------------------------
__global__ __launch_bounds__(512) void qkv_gemm_kernel(
    const bf16* __restrict__ xb, const bf16* __restrict__ wqkvb,
    const float* __restrict__ bias,
    bf16* __restrict__ qh, bf16* __restrict__ kh, bf16* __restrict__ vT)
{
    __shared__ bf16 lds[8 * 8192];        // 8 halftile slots x 16 KB
    const int tid = threadIdx.x;
    const int bn = blockIdx.x, bm = blockIdx.y;
    const int lane = tid & 63, quad = lane >> 4, lcol = lane & 15;
    const int wave = tid >> 6;
    const int wm = wave >> 1;             // 0..3: rows 64*wm..+64
    const int wn = wave & 1;              // 0..1: cols 128*wn..+128
    const int rdoff = ((quad ^ ((lcol >> 1) & 3)) << 3);   // swizzled chunk

    // staging: thread covers (row = tid>>2 and +128, chunk = tid&3)
    const int srow = tid >> 2, sch = tid & 3;
    const int gsw = (sch ^ ((srow >> 1) & 3)) << 3;        // pre-swizzled src col
    const bf16* ga = xb    + (size_t)(bm * 256 + srow) * D_ + gsw;
    const bf16* gb = wqkvb + (size_t)(bn * 256 + srow) * D_ + gsw;
    bf16* ldst = lds + tid * 8;           // linear dest (= srow*32 + sch*8)

    // kind: 0=A,k0  1=B,k0  2=A,k1  3=B,k1 ; slot = (t&1)*4 + kind
#define STAGE(T, KIND)                                                         \
    {                                                                          \
        const bf16* g_ = (((KIND) & 1) ? gb : ga) + (T) * 64 + ((KIND) >> 1) * 32; \
        bf16* d_ = ldst + (((T) & 1) * 4 + (KIND)) * 8192;                     \
        glds16(g_, d_);                                                        \
        glds16(g_ + (size_t)128 * D_, d_ + 4096);                              \
    }

    f32x4 acc[4][8];
    const f32x4 z = {0.f, 0.f, 0.f, 0.f};
#pragma unroll
    for (int i = 0; i < 4; i++)
#pragma unroll
        for (int j = 0; j < 8; j++) acc[i][j] = z;

    const int NT = D_ / 64;               // 32 K-tiles

    // prologue: all 4 halftiles of tile 0 -> 8 loads; wait oldest 4 (Ak0,Bk0)
    STAGE(0, 0); STAGE(0, 1); STAGE(0, 2); STAGE(0, 3);
    __builtin_amdgcn_sched_barrier(0);    // pin: all 8 issued before the count
    asm volatile("s_waitcnt vmcnt(4)" ::: "memory");
    __builtin_amdgcn_s_barrier();

    // one fine phase: reads for one 16-MFMA quadrant + 1 halftile stage
#define PHASE(PA, PB, JBASE, RD_A, T1, KIND, GUARD, LASTT)                     \
    {                                                                          \
        bf16x8 bfr[4];                                                         \
        if (RD_A) {                                                            \
            _Pragma("unroll")                                                  \
            for (int i = 0; i < 4; i++)                                        \
                af[i] = *(const bf16x8*)&(PA)[(wm * 64 + i * 16 + lcol) * 32 + rdoff]; \
        }                                                                      \
        _Pragma("unroll")                                                      \
        for (int j = 0; j < 4; j++)                                            \
            bfr[j] = *(const bf16x8*)&(PB)[(wn * 128 + (JBASE + j) * 16 + lcol) * 32 + rdoff]; \
        if (!(LASTT)) STAGE(T1, KIND);                                         \
        if (GUARD) {                                                           \
            __builtin_amdgcn_sched_barrier(0);  /* pin issue order vs count */ \
            if (LASTT) asm volatile("s_waitcnt vmcnt(0)" ::: "memory");        \
            else       asm volatile("s_waitcnt vmcnt(4)" ::: "memory");        \
        }                                                                      \
        __builtin_amdgcn_s_barrier();                                          \
        asm volatile("s_waitcnt lgkmcnt(0)" ::: "memory");                     \
        __builtin_amdgcn_sched_barrier(0);                                     \
        __builtin_amdgcn_s_setprio(1);                                         \
        _Pragma("unroll")                                                      \
        for (int j = 0; j < 4; j++)                                            \
            _Pragma("unroll")                                                  \
            for (int i = 0; i < 4; i++)                                        \
                acc[i][JBASE + j] = __builtin_amdgcn_mfma_f32_16x16x32_bf16(   \
                    af[i], bfr[j], acc[i][JBASE + j], 0, 0, 0);                \
        __builtin_amdgcn_s_setprio(0);                                         \
        __builtin_amdgcn_sched_barrier(0);                                     \
        __builtin_amdgcn_s_barrier();                                         \
    }

#define QKV_TILE(T, PAR, LASTT)                                                \
    {                                                                          \
        const bf16* pa0 = lds + ((PAR) + 0) * 8192;                            \
        const bf16* pb0 = lds + ((PAR) + 1) * 8192;                            \
        const bf16* pa1 = lds + ((PAR) + 2) * 8192;                            \
        const bf16* pb1 = lds + ((PAR) + 3) * 8192;                            \
        bf16x8 af[4];                                                          \
        PHASE(pa0, pb0, 0, true,  (T) + 1, 0, false, LASTT)  /* j0-3  k0 */    \
        PHASE(pa0, pb0, 4, false, (T) + 1, 1, true,  LASTT)  /* j4-7  k0 */    \
        PHASE(pa1, pb1, 0, true,  (T) + 1, 2, false, LASTT)  /* j0-3  k1 */    \
        PHASE(pa1, pb1, 4, false, (T) + 1, 3, !(LASTT), LASTT) /* j4-7 k1 */   \
    }

    for (int t2 = 0; t2 < 15; t2++) {
        QKV_TILE(2 * t2, 0, false);
        QKV_TILE(2 * t2 + 1, 4, false);
    }
    QKV_TILE(30, 0, false);
    QKV_TILE(31, 4, true);
#undef QKV_TILE
#undef PHASE
#undef STAGE

    // ---- epilogue: col(j) = j*16 + lcol, j/j+4 are 64 apart (RoPE pairs) ----
    const int n0 = bn * 256 + wn * 128;
    const int part = bn >> 3;             // 0=q 1=k 2=v
    const int hh = (bn & 7) * 2 + wn;
    const int mb0 = bm * 256 + wm * 64;
    const int bb = mb0 >> 11, tb = mb0 & (T_ - 1);

    if (part < 2) {
        bf16* dst = (part == 0) ? qh : kh;
#pragma unroll
        for (int jp = 0; jp < 4; jp++) {
            const int d1 = jp * 16 + lcol;
            const float invf = __expf(-0.14391156831212787f * (float)d1);
            const float b1 = bias[n0 + d1];
            const float b2 = bias[n0 + d1 + 64];
#pragma unroll
            for (int i = 0; i < 4; i++) {
#pragma unroll
                for (int r = 0; r < 4; r++) {
                    const int t = tb + i * 16 + quad * 4 + r;
                    const float x1 = acc[i][jp][r] + b1;
                    const float x2 = acc[i][jp + 4][r] + b2;
                    float s, c;
                    __sincosf((float)t * invf, &s, &c);
                    const size_t rowo = ((size_t)(bb * H_ + hh) * T_ + t) * HD_;
                    dst[rowo + d1]      = (bf16)(x1 * c - x2 * s);
                    dst[rowo + d1 + 64] = (bf16)(x1 * s + x2 * c);
                }
            }
        }
    } else {
        const int bh = bb * H_ + hh;
#pragma unroll
        for (int j = 0; j < 8; j++) {
            const int d = j * 16 + lcol;
            const float bv = bias[n0 + d];
            bf16* vdst = &vT[((size_t)bh * HD_ + d) * T_ + tb];
#pragma unroll
            for (int r = 0; r < 4; r++) {
                union { bf16 hhv[4]; ushort4 u; } pk;
#pragma unroll
                for (int i = 0; i < 4; i++) pk.hhv[i] = (bf16)(acc[i][j][r] + bv);
                *(ushort4*)&vdst[(quad * 4 + r) * 4] = pk.u;
            }
        }
    }
}

// ---------------------------------------------------------------------------
// Flash attention (causal), R11 structure: R7 inner loop + uniform 64-row
// tile pairs (qt, 31-qt) -> 33 steps/block, 512 blocks, 2 blocks/CU.
// ---------------------------------------------------------------------------
__global__ __launch_bounds__(256) void attn_kernel(
    const bf16* __restrict__ qh, const bf16* __restrict__ kh,
    const bf16* __restrict__ vT, bf16* __restrict__ ctx)
{
    __shared__ bf16 lds_k[2][64 * 128];
    __shared__ bf16 lds_v[2][128 * 64];
    __shared__ bf16 lds_p[64 * 64];
    const int tid = threadIdx.x;
    const int id = blockIdx.x;
    const int bh = id & 31;
    const int qp = id >> 5;
    const int qtA = 31 - qp;
    const int qtB = qp;
    const int ktA = qtA + 1;
    const int lane = tid & 63, quad = lane >> 4, lcol = lane & 15;
    const int wave = tid >> 6;
    const int wq0 = wave * 16;
    const float scale2 = 0.08838834764831845f * 1.4426950408889634f;
    const int b = bh >> 4, h = bh & 15;

    const bf16* kbase = kh + (size_t)bh * T_ * HD_;
    const bf16* vbase = vT + (size_t)bh * HD_ * T_;

    const int ksrow = tid >> 4;
    const bf16* kstage = kbase + (size_t)ksrow * HD_ + (((tid & 15) ^ ksrow) << 3);
    const int vsd = tid >> 3;
    const bf16* vstage = vbase + (size_t)vsd * T_ + (((tid & 7) ^ (vsd & 7)) << 3);

    int qt_cur = qtA;
    int q0 = qtA * 64;

    bf16x8 qf[4];
    auto load_q = [&](int q0_) {
#pragma unroll
        for (int kk = 0; kk < 4; kk++)
            qf[kk] = *(const bf16x8*)&qh[((size_t)bh * T_ + q0_ + wq0 + lcol) * HD_ +
                                         kk * 32 + quad * 8];
    };
    load_q(q0);

    f32x4 o[8];
    const f32x4 z = {0.f, 0.f, 0.f, 0.f};
#pragma unroll
    for (int jd = 0; jd < 8; jd++) o[jd] = z;
    float l_part[4] = {0.f, 0.f, 0.f, 0.f};

    auto do_epilogue = [&](int q0_) {
        float inv_l[4];
#pragma unroll
        for (int r = 0; r < 4; r++) {
            float rs = l_part[r];
#pragma unroll
            for (int off = 1; off < 16; off <<= 1)
                rs += __shfl_xor(rs, off);
            inv_l[r] = 1.0f / rs;
        }
#pragma unroll
        for (int r = 0; r < 4; r++) {
            const int t = q0_ + wq0 + quad * 4 + r;
#pragma unroll
            for (int jd = 0; jd < 8; jd++)
                ctx[((size_t)(b * T_ + t)) * D_ + h * HD_ + jd * 16 + lcol] =
                    (bf16)(o[jd][r] * inv_l[r]);
        }
    };

#pragma unroll
    for (int p = 0; p < 4; p++) {
        glds16(kstage + (size_t)16 * p * HD_, &lds_k[0][tid * 8 + p * 2048]);
        glds16(vstage + (size_t)32 * p * T_, &lds_v[0][tid * 8 + p * 2048]);
    }

    for (int s = 0; s < 33; s++) {
        __syncthreads();
        if (s + 1 < 33) {
            const int kn = (s + 1 < ktA) ? (s + 1) : (s + 1 - ktA);
            const bf16* ks = kstage + (size_t)kn * 64 * HD_;
            const bf16* vs = vstage + kn * 64;
            bf16* lkd = &lds_k[(s + 1) & 1][tid * 8];
            bf16* lvd = &lds_v[(s + 1) & 1][tid * 8];
#pragma unroll
            for (int p = 0; p < 4; p++) {
                glds16(ks + (size_t)16 * p * HD_, lkd + p * 2048);
                glds16(vs + (size_t)32 * p * T_, lvd + p * 2048);
            }
        }
        if (s == ktA) {
            do_epilogue(q0);
            qt_cur = qtB;
            q0 = qtB * 64;
            load_q(q0);
#pragma unroll
            for (int jd = 0; jd < 8; jd++) o[jd] = z;
#pragma unroll
            for (int r = 0; r < 4; r++) l_part[r] = 0.f;
        }
        const int kt = (s < ktA) ? s : (s - ktA);
        const bf16* lk = lds_k[s & 1];
        const bf16* lv = lds_v[s & 1];

        f32x4 s_acc[4];
#pragma unroll
        for (int j = 0; j < 4; j++) s_acc[j] = z;
        __builtin_amdgcn_s_setprio(1);
#pragma unroll
        for (int kk = 0; kk < 4; kk++) {
#pragma unroll
            for (int j = 0; j < 4; j++) {
                const bf16x8 bk = *(const bf16x8*)&lk[(j * 16 + lcol) * 128 +
                                        (((kk * 4 + quad) ^ lcol) << 3)];
                s_acc[j] = __builtin_amdgcn_mfma_f32_16x16x32_bf16(qf[kk], bk, s_acc[j], 0, 0, 0);
            }
        }
        __builtin_amdgcn_s_setprio(0);

        const bool diag = (kt == qt_cur);
#pragma unroll
        for (int r = 0; r < 4; r++) {
            const int prow = wq0 + quad * 4 + r;
            const int qrow = q0 + prow;
            union { bf16 hh[4]; ushort4 u; } pk;
            float lp = 0.f;
#pragma unroll
            for (int j = 0; j < 4; j++) {
                float p = exp2f(fmaf(s_acc[j][r], scale2, -16.0f));
                if (diag) {
                    const int kcol = kt * 64 + j * 16 + lcol;
                    p = (kcol > qrow) ? 0.f : p;
                }
                lp += p;
                pk.hh[j] = (bf16)p;
            }
            l_part[r] += lp;
            *(ushort4*)&lds_p[prow * 64 + ((lcol * 4) ^ ((prow & 7) << 3))] = pk.u;
        }

#pragma unroll
        for (int kk2 = 0; kk2 < 2; kk2++) {
            const int prow = wq0 + lcol;
            const bf16x8 pf = *(const bf16x8*)&lds_p[prow * 64 +
                                  ((kk2 * 32 + quad * 8) ^ ((lcol & 7) << 3))];
            bf16x8 vf[8];
#pragma unroll
            for (int jd = 0; jd < 8; jd++) {
                const int d = jd * 16 + lcol;
                vf[jd] = *(const bf16x8*)&lv[d * 64 +
                              (((kk2 * 4 + quad) ^ (lcol & 7)) << 3)];
            }
            __builtin_amdgcn_s_setprio(1);
#pragma unroll
            for (int jd = 0; jd < 8; jd++)
                o[jd] = __builtin_amdgcn_mfma_f32_16x16x32_bf16(pf, vf[jd], o[jd], 0, 0, 0);
            __builtin_amdgcn_s_setprio(0);
        }
    }

    do_epilogue(q0);
}

// ---------------------------------------------------------------------------
// Output projection: out = ctx @ Wo^T + bo  (bf16 x bf16 -> fp32 out)
// ---------------------------------------------------------------------------
__global__ __launch_bounds__(256) void proj_gemm_kernel(
    const bf16* __restrict__ ctx, const bf16* __restrict__ wob,
    const float* __restrict__ bias, float* __restrict__ out)
{
    __shared__ bf16 lds_a[128 * 64];
    __shared__ bf16 lds_b[128 * 64];
    const int tid = threadIdx.x;
    const int bm = blockIdx.y, bn = blockIdx.x;
    const int lane = tid & 63, quad = lane >> 4, lcol = lane & 15;
    const int wave = tid >> 6;
    const int wm = (wave >> 1) * 64, wn2 = (wave & 1) * 32;

    f32x4 acc[4][4];
    const f32x4 z = {0.f, 0.f, 0.f, 0.f};
#pragma unroll
    for (int i = 0; i < 4; i++)
#pragma unroll
        for (int j = 0; j < 4; j++) acc[i][j] = z;

    gemm_core_glds(ctx, wob, D_, bm, bn, tid, acc, lds_a, lds_b);

    const int n0 = bn * 128;
#pragma unroll
    for (int i = 0; i < 4; i++) {
#pragma unroll
        for (int j = 0; j < 4; j++) {
            const int n = n0 + wn2 + (j & 1) * 16 + (j >> 1) * 64 + lcol;
            const float bv = bias[n];
#pragma unroll
            for (int r = 0; r < 4; r++) {
                const int m = bm * 128 + wm + i * 16 + quad * 4 + r;
                out[(size_t)m * D_ + n] = acc[i][j][r] + bv;
            }
        }
    }
}

extern "C" void kernel_launch(void* const* d_in, const int* in_sizes, int n_in,
                              void* d_out, int out_size, void* d_ws, size_t ws_size,
                              hipStream_t stream)
{
    const float* x    = (const float*)d_in[0];
    const float* Wqkv = (const float*)d_in[1];
    const float* bqkv = (const float*)d_in[2];
    const float* Wo   = (const float*)d_in[3];
    const float* bo   = (const float*)d_in[4];
    float* out = (float*)d_out;

    const size_t HT = (size_t)B_ * H_ * T_ * HD_;
    bf16* xb   = (bf16*)d_ws;
    bf16* qh   = xb + HT;
    bf16* kh   = qh + HT;
    bf16* vT   = kh + HT;
    bf16* ctx  = xb;
    bf16* wob  = qh;
    bf16* wqkvb = (bf16*)d_out;

    convert_xw_kernel<<<2560, 256, 0, stream>>>(x, Wqkv, xb, wqkvb);
    // 256^2 fine-phase counted-vmcnt GEMM, 384 blocks x 512 threads
    qkv_gemm_kernel<<<dim3(24, 16), 512, 0, stream>>>(xb, wqkvb, bqkv, qh, kh, vT);
    attn_kernel<<<512, 256, 0, stream>>>(qh, kh, vT, ctx);
    convert_wo_kernel<<<1024, 256, 0, stream>>>(Wo, wob);
    proj_gemm_kernel<<<dim3(16, 32), 256, 0, stream>>>(ctx, wob, bo, out);
}

// Round 11
// 355.377 us; speedup vs baseline: 1.0344x; 1.0117x over previous
//
#include <hip/hip_runtime.h>
#include <hip/hip_bf16.h>
#include <cstdint>

typedef __bf16 bf16;
typedef __bf16 bf16x8 __attribute__((ext_vector_type(8)));
typedef float  f32x4  __attribute__((ext_vector_type(4)));

#define B_   2
#define T_   2048
#define D_   2048
#define H_   16
#define HD_  128

// async global->LDS, 16 B per lane (m97: the 874 TF enabler).
// LDS dest must be wave-uniform base + lane*16 -> lanes stay contiguous in
// physical-slot order; we permute the GLOBAL side per-lane for XOR swizzles.
typedef __attribute__((address_space(3))) void       lds_void;
typedef __attribute__((address_space(1))) const void gbl_void;
__device__ __forceinline__ void glds16(const bf16* g, bf16* l) {
    __builtin_amdgcn_global_load_lds((gbl_void*)g, (lds_void*)l, 16, 0, 0);
}

// ---------------------------------------------------------------------------
// fp32 -> bf16 pre-convert (grid-stride, float4 -> 4x bf16 pack)
// ---------------------------------------------------------------------------
__device__ __forceinline__ ushort4 cvt4(const float4 v) {
    union { bf16 h[4]; ushort4 u; } pk;
    pk.h[0] = (bf16)v.x; pk.h[1] = (bf16)v.y;
    pk.h[2] = (bf16)v.z; pk.h[3] = (bf16)v.w;
    return pk.u;
}

__global__ __launch_bounds__(256) void convert_xw_kernel(
    const float* __restrict__ x, const float* __restrict__ wqkv,
    bf16* __restrict__ xb, bf16* __restrict__ wqkvb)
{
    const int NX = (B_ * T_ * D_) / 4;          // 2,097,152 float4
    const int NT = NX + (3 * D_ * D_) / 4;      // + 3,145,728
    for (int g = blockIdx.x * blockDim.x + threadIdx.x; g < NT;
         g += gridDim.x * blockDim.x) {
        if (g < NX) ((ushort4*)xb)[g]      = cvt4(((const float4*)x)[g]);
        else        ((ushort4*)wqkvb)[g-NX] = cvt4(((const float4*)wqkv)[g-NX]);
    }
}

__global__ __launch_bounds__(256) void convert_wo_kernel(
    const float* __restrict__ wo, bf16* __restrict__ wob)
{
    const int N = (D_ * D_) / 4;                // 1,048,576 float4
    for (int g = blockIdx.x * blockDim.x + threadIdx.x; g < N;
         g += gridDim.x * blockDim.x)
        ((ushort4*)wob)[g] = cvt4(((const float4*)wo)[g]);
}

// ---------------------------------------------------------------------------
// m97-style NT-GEMM core with XOR-swizzled LDS: C[128x128], A[M][K], W[N][K]
// bf16 K-major, global_load_lds width-16 staging into [128][64] tiles.
// Measured: 852 TF on the qkv shape (the m97 2-barrier structure's ceiling);
// 3 rounds of 256^2 8-phase rewrites (R12/R13/R15) all measured <= this.
// ---------------------------------------------------------------------------
__device__ __forceinline__ void gemm_core_glds(
    const bf16* __restrict__ A, const bf16* __restrict__ W, int K,
    int bm, int bn, int tid, f32x4 (&acc)[4][4],
    bf16* lds_a, bf16* lds_b)
{
    const int lane = tid & 63, quad = lane >> 4, lcol = lane & 15;
    const int wave = tid >> 6;
    const int wm = (wave >> 1) * 64, wn2 = (wave & 1) * 32;
    const int sw = lcol & 7;                          // read-side swizzle key
    const int sr = tid >> 3, pc = tid & 7;            // staging row / physical chunk
    const int sc = (pc ^ (sr & 7)) * 8;               // logical col group fetched
    const bf16* abase = A + (size_t)(bm * 128 + sr) * K + sc;
    const bf16* bbase = W + (size_t)(bn * 128 + sr) * K + sc;
    bf16* la = lds_a + sr * 64 + pc * 8;              // = lds_a + tid*8 elems
    bf16* lb = lds_b + sr * 64 + pc * 8;

    for (int k0 = 0; k0 < K; k0 += 64) {
        __syncthreads();
#pragma unroll
        for (int p = 0; p < 4; p++) {                 // (sr+32p)&7 == sr&7
            glds16(abase + k0 + (size_t)32 * p * K, la + 2048 * p);
            glds16(bbase + k0 + (size_t)32 * p * K, lb + 2048 * p);
        }
        __syncthreads();
#pragma unroll
        for (int kk = 0; kk < 2; kk++) {
            bf16x8 af[4], bfr[4];
#pragma unroll
            for (int i = 0; i < 4; i++)
                af[i] = *(const bf16x8*)&lds_a[(wm + i * 16 + lcol) * 64 +
                                               (((kk * 4 + quad) ^ sw) * 8)];
#pragma unroll
            for (int j = 0; j < 4; j++) {
                const int row = wn2 + (j & 1) * 16 + (j >> 1) * 64 + lcol;
                bfr[j] = *(const bf16x8*)&lds_b[row * 64 +
                                                (((kk * 4 + quad) ^ sw) * 8)];
            }
#pragma unroll
            for (int i = 0; i < 4; i++)
#pragma unroll
                for (int j = 0; j < 4; j++)
                    acc[i][j] = __builtin_amdgcn_mfma_f32_16x16x32_bf16(af[i], bfr[j], acc[i][j], 0, 0, 0);
        }
    }
}

// ---------------------------------------------------------------------------
// QKV projection (bf16 in via pre-convert) + fused RoPE + head scatter:
//   q,k -> [bh][t][d] with rotary applied;  v -> vT[bh][d][t]
// vT keys are PI-PERMUTED within each 64-t block: phys(t) = (t&15)*4 + (t>>4)
// -> attn's P-store is a packed ushort4 and V reads stay bf16x8-contiguous.
// ---------------------------------------------------------------------------
__global__ __launch_bounds__(256) void qkv_gemm_kernel(
    const bf16* __restrict__ xb, const bf16* __restrict__ wqkvb,
    const float* __restrict__ bias,
    bf16* __restrict__ qh, bf16* __restrict__ kh, bf16* __restrict__ vT)
{
    __shared__ bf16 lds_a[128 * 64];
    __shared__ bf16 lds_b[128 * 64];
    const int tid = threadIdx.x;
    const int bm = blockIdx.y, bn = blockIdx.x;
    const int lane = tid & 63, quad = lane >> 4, lcol = lane & 15;
    const int wave = tid >> 6;
    const int wm = (wave >> 1) * 64, wn2 = (wave & 1) * 32;

    f32x4 acc[4][4];
    const f32x4 z = {0.f, 0.f, 0.f, 0.f};
#pragma unroll
    for (int i = 0; i < 4; i++)
#pragma unroll
        for (int j = 0; j < 4; j++) acc[i][j] = z;

    gemm_core_glds(xb, wqkvb, D_, bm, bn, tid, acc, lds_a, lds_b);

    const int n0 = bn * 128;
    const int part = bn / 16;            // 0=q 1=k 2=v (block-uniform)
    const int h = bn & 15;
    const int mb0 = bm * 128 + wm;       // 64-aligned -> one batch, one 64-blk

    if (part < 2) {
        bf16* dst = (part == 0) ? qh : kh;
#pragma unroll
        for (int i = 0; i < 4; i++) {
#pragma unroll
            for (int jp = 0; jp < 2; jp++) {
                const int d1 = wn2 + jp * 16 + lcol;       // 0..63
                const float invf = __expf(-0.14391156831212787f * (float)d1);
                const float b1 = bias[n0 + d1];
                const float b2 = bias[n0 + d1 + 64];
#pragma unroll
                for (int r = 0; r < 4; r++) {
                    const int m = mb0 + i * 16 + quad * 4 + r;
                    const int bb = m >> 11, t = m & (T_ - 1);
                    const float x1 = acc[i][jp][r] + b1;       // d1
                    const float x2 = acc[i][jp + 2][r] + b2;   // d1 + 64
                    float s, c;
                    __sincosf((float)t * invf, &s, &c);
                    const size_t rowo = ((size_t)(bb * H_ + h) * T_ + t) * HD_;
                    dst[rowo + d1]      = (bf16)(x1 * c - x2 * s);
                    dst[rowo + d1 + 64] = (bf16)(x1 * s + x2 * c);
                }
            }
        }
    } else {
        const int bb = mb0 >> 11, t64 = mb0 & (T_ - 1);   // 64-aligned t base
        const int bh = bb * H_ + h;
#pragma unroll
        for (int j = 0; j < 4; j++) {
            const int d = wn2 + (j & 1) * 16 + (j >> 1) * 64 + lcol;
            const float bv = bias[n0 + d];
            bf16* vdst = &vT[((size_t)bh * HD_ + d) * T_ + t64];
#pragma unroll
            for (int r = 0; r < 4; r++) {
                union { bf16 hh[4]; ushort4 u; } pk;
#pragma unroll
                for (int i = 0; i < 4; i++) pk.hh[i] = (bf16)(acc[i][j][r] + bv);
                // phys(t=i*16+quad*4+r) = (quad*4+r)*4 + i  -> contiguous in i
                *(ushort4*)&vdst[(quad * 4 + r) * 4] = pk.u;
            }
        }
    }
}

// ---------------------------------------------------------------------------
// Flash attention (causal), R7 structure (session-best, total 351.6us):
//  * 64-row q blocks, grid 1024 (32bh x 32 q-tiles), 16 rows/wave,
//    2 blocks/CU with a 512-block backfill queue.
//  * K tile AND V tile double-buffered in LDS via glds16 w/ global-side
//    XOR swizzle; prefetch of tile kt+1 issued at top of tile kt.
//  * pi-permuted packed P (ushort4 stores), no-max softmax
//    (p = exp2(s*scale*log2e - 16), exact-pow2 shift cancels in o/l),
//    diag-only masking, setprio around MFMA clusters.
// LDS: 2*16KB (K) + 2*16KB (V) + 8KB (P) = 72KB -> 2 blocks/CU, 8 waves/CU.
// Schedule variants measured and rejected: LPT order (R9 +14us), 128-row
// blocks (R8 +23us), 1-blk/CU uniform pairs (R10 +37us), 2-blk/CU uniform
// pairs (R11 +3us).
// ---------------------------------------------------------------------------
__global__ __launch_bounds__(256) void attn_kernel(
    const bf16* __restrict__ qh, const bf16* __restrict__ kh,
    const bf16* __restrict__ vT, bf16* __restrict__ ctx)
{
    __shared__ bf16 lds_k[2][64 * 128];   // [key][d], XOR-swizzled
    __shared__ bf16 lds_v[2][128 * 64];   // [d][phys-key], XOR-swizzled
    __shared__ bf16 lds_p[64 * 64];       // P (phys-key order), wave-private rows
    const int tid = threadIdx.x;
    const int id = blockIdx.x;            // 1024 = 32 bh x 32 q-tiles
    const int bh = id & 31;
    const int q5 = (id >> 5) & 15;
    const int qt = (id >> 9) ? (31 - q5) : q5;
    const int q0 = qt * 64;
    const int lane = tid & 63, quad = lane >> 4, lcol = lane & 15;
    const int wave = tid >> 6;
    const int wq0 = wave * 16;
    const float scale2 = 0.08838834764831845f * 1.4426950408889634f;

    const bf16* kbase = kh + (size_t)bh * T_ * HD_;
    const bf16* vbase = vT + (size_t)bh * HD_ * T_;

    // K staging: row srow+16p, chunk tid&15; src col chunk ^ (row&15).
    const int ksrow = tid >> 4;                        // 0..15
    const bf16* kstage = kbase + (size_t)ksrow * HD_ + (((tid & 15) ^ ksrow) << 3);
    // V staging: d row vsd+32p, chunk tid&7; src key chunk ^ (d&7).
    const int vsd = tid >> 3;                          // 0..31
    const bf16* vstage = vbase + (size_t)vsd * T_ + (((tid & 7) ^ (vsd & 7)) << 3);

    // Q fragments in registers (A-operand layout, straight from global)
    bf16x8 qf[4];
#pragma unroll
    for (int kk = 0; kk < 4; kk++)
        qf[kk] = *(const bf16x8*)&qh[((size_t)bh * T_ + q0 + wq0 + lcol) * HD_ +
                                     kk * 32 + quad * 8];

    f32x4 o[8];
    const f32x4 z = {0.f, 0.f, 0.f, 0.f};
#pragma unroll
    for (int jd = 0; jd < 8; jd++) o[jd] = z;
    float l_part[4] = {0.f, 0.f, 0.f, 0.f};

    const int ktmax = qt + 1;             // block-uniform
    // prologue: stage tile 0 into buf 0
#pragma unroll
    for (int p = 0; p < 4; p++) {
        glds16(kstage + (size_t)16 * p * HD_, &lds_k[0][tid * 8 + p * 2048]);
        glds16(vstage + (size_t)32 * p * T_, &lds_v[0][tid * 8 + p * 2048]);
    }

    for (int kt = 0; kt < ktmax; kt++) {
        __syncthreads();                  // stage(kt) landed; buf^1 reads done
        if (kt + 1 < ktmax) {             // prefetch kt+1 (block-uniform)
            const bf16* ks = kstage + (size_t)(kt + 1) * 64 * HD_;
            const bf16* vs = vstage + (kt + 1) * 64;
            bf16* lkd = &lds_k[(kt + 1) & 1][tid * 8];
            bf16* lvd = &lds_v[(kt + 1) & 1][tid * 8];
#pragma unroll
            for (int p = 0; p < 4; p++) {
                glds16(ks + (size_t)16 * p * HD_, lkd + p * 2048);
                glds16(vs + (size_t)32 * p * T_, lvd + p * 2048);
            }
        }
        const bf16* lk = lds_k[kt & 1];
        const bf16* lv = lds_v[kt & 1];

        // ---- QK^T: K B-fragments from swizzled LDS ----
        f32x4 s_acc[4];
#pragma unroll
        for (int j = 0; j < 4; j++) s_acc[j] = z;
        __builtin_amdgcn_s_setprio(1);
#pragma unroll
        for (int kk = 0; kk < 4; kk++) {
#pragma unroll
            for (int j = 0; j < 4; j++) {
                const bf16x8 bk = *(const bf16x8*)&lk[(j * 16 + lcol) * 128 +
                                        (((kk * 4 + quad) ^ lcol) << 3)];
                s_acc[j] = __builtin_amdgcn_mfma_f32_16x16x32_bf16(qf[kk], bk, s_acc[j], 0, 0, 0);
            }
        }
        __builtin_amdgcn_s_setprio(0);

        // ---- no-max softmax; packed P store in pi-permuted key order ----
        const bool diag = (kt == qt);
#pragma unroll
        for (int r = 0; r < 4; r++) {
            const int prow = wq0 + quad * 4 + r;      // P row (q-local)
            const int qrow = q0 + prow;               // global q row
            union { bf16 hh[4]; ushort4 u; } pk;
            float lp = 0.f;
#pragma unroll
            for (int j = 0; j < 4; j++) {
                float p = exp2f(fmaf(s_acc[j][r], scale2, -16.0f));
                if (diag) {
                    const int kcol = kt * 64 + j * 16 + lcol;
                    p = (kcol > qrow) ? 0.f : p;
                }
                lp += p;
                pk.hh[j] = (bf16)p;      // phys key = lcol*4 + j
            }
            l_part[r] += lp;
            *(ushort4*)&lds_p[prow * 64 + ((lcol * 4) ^ ((prow & 7) << 3))] = pk.u;
        }

        // ---- PV: P and V both from LDS (short, stall-free path) ----
#pragma unroll
        for (int kk2 = 0; kk2 < 2; kk2++) {
            const int prow = wq0 + lcol;
            const bf16x8 pf = *(const bf16x8*)&lds_p[prow * 64 +
                                  ((kk2 * 32 + quad * 8) ^ ((lcol & 7) << 3))];
            bf16x8 vf[8];
#pragma unroll
            for (int jd = 0; jd < 8; jd++) {
                const int d = jd * 16 + lcol;
                vf[jd] = *(const bf16x8*)&lv[d * 64 +
                              (((kk2 * 4 + quad) ^ (lcol & 7)) << 3)];
            }
            __builtin_amdgcn_s_setprio(1);
#pragma unroll
            for (int jd = 0; jd < 8; jd++)
                o[jd] = __builtin_amdgcn_mfma_f32_16x16x32_bf16(pf, vf[jd], o[jd], 0, 0, 0);
            __builtin_amdgcn_s_setprio(0);
        }
    }

    // final l reduction: 16 lanes of the quad hold partials of the same q-row
    float inv_l[4];
#pragma unroll
    for (int r = 0; r < 4; r++) {
        float rs = l_part[r];
#pragma unroll
        for (int off = 1; off < 16; off <<= 1)
            rs += __shfl_xor(rs, off);
        inv_l[r] = 1.0f / rs;
    }
    // epilogue: ctx[(b*T + t)][h*HD + d], row-major D for the proj GEMM
    const int b = bh >> 4, h = bh & 15;
#pragma unroll
    for (int r = 0; r < 4; r++) {
        const int t = q0 + wq0 + quad * 4 + r;
#pragma unroll
        for (int jd = 0; jd < 8; jd++)
            ctx[((size_t)(b * T_ + t)) * D_ + h * HD_ + jd * 16 + lcol] =
                (bf16)(o[jd][r] * inv_l[r]);
    }
}

// ---------------------------------------------------------------------------
// Output projection: out = ctx @ Wo^T + bo  (bf16 x bf16 -> fp32 out)
// ---------------------------------------------------------------------------
__global__ __launch_bounds__(256) void proj_gemm_kernel(
    const bf16* __restrict__ ctx, const bf16* __restrict__ wob,
    const float* __restrict__ bias, float* __restrict__ out)
{
    __shared__ bf16 lds_a[128 * 64];
    __shared__ bf16 lds_b[128 * 64];
    const int tid = threadIdx.x;
    const int bm = blockIdx.y, bn = blockIdx.x;
    const int lane = tid & 63, quad = lane >> 4, lcol = lane & 15;
    const int wave = tid >> 6;
    const int wm = (wave >> 1) * 64, wn2 = (wave & 1) * 32;

    f32x4 acc[4][4];
    const f32x4 z = {0.f, 0.f, 0.f, 0.f};
#pragma unroll
    for (int i = 0; i < 4; i++)
#pragma unroll
        for (int j = 0; j < 4; j++) acc[i][j] = z;

    gemm_core_glds(ctx, wob, D_, bm, bn, tid, acc, lds_a, lds_b);

    const int n0 = bn * 128;
#pragma unroll
    for (int i = 0; i < 4; i++) {
#pragma unroll
        for (int j = 0; j < 4; j++) {
            const int n = n0 + wn2 + (j & 1) * 16 + (j >> 1) * 64 + lcol;
            const float bv = bias[n];
#pragma unroll
            for (int r = 0; r < 4; r++) {
                const int m = bm * 128 + wm + i * 16 + quad * 4 + r;
                out[(size_t)m * D_ + n] = acc[i][j][r] + bv;
            }
        }
    }
}

extern "C" void kernel_launch(void* const* d_in, const int* in_sizes, int n_in,
                              void* d_out, int out_size, void* d_ws, size_t ws_size,
                              hipStream_t stream)
{
    const float* x    = (const float*)d_in[0];
    const float* Wqkv = (const float*)d_in[1];
    const float* bqkv = (const float*)d_in[2];
    const float* Wo   = (const float*)d_in[3];
    const float* bo   = (const float*)d_in[4];
    // d_in[5] = mask — causal, computed analytically in-kernel.
    float* out = (float*)d_out;

    const size_t HT = (size_t)B_ * H_ * T_ * HD_;   // 8,388,608 elems
    // d_ws (67.1 MB, proven size): [xb|ctx][qh|wob][kh][vT]
    bf16* xb   = (bf16*)d_ws;
    bf16* qh   = xb + HT;
    bf16* kh   = qh + HT;
    bf16* vT   = kh + HT;
    bf16* ctx  = xb;             // xb dead after qkv gemm
    bf16* wob  = qh;             // qh dead after attn
    // d_out (33.55 MB fp32): holds bf16 Wqkv (25.2 MB) until proj overwrites
    bf16* wqkvb = (bf16*)d_out;

    // 1) fp32 -> bf16 pre-convert of x and Wqkv
    convert_xw_kernel<<<2560, 256, 0, stream>>>(x, Wqkv, xb, wqkvb);
    // 2) QKV projection + fused RoPE + head scatter (vT pi-permuted keys)
    qkv_gemm_kernel<<<dim3(48, 32), 256, 0, stream>>>(xb, wqkvb, bqkv, qh, kh, vT);
    // 3) causal flash attention -> ctx: K+V LDS dbuf, 1024 blocks, 2 blk/CU
    attn_kernel<<<1024, 256, 0, stream>>>(qh, kh, vT, ctx);
    // 4) Wo -> bf16 into dead qh region
    convert_wo_kernel<<<1024, 256, 0, stream>>>(Wo, wob);
    // 5) output projection -> fp32 out (overwrites wqkvb region)
    proj_gemm_kernel<<<dim3(16, 32), 256, 0, stream>>>(ctx, wob, bo, out);
}